// Round 10
// baseline (390.518 us; speedup 1.0000x reference)
//
#include <hip/hip_runtime.h>
#include <hip/hip_fp16.h>

// Problem constants (fixed by the reference)
#define N_NODES   50000
#define N_EDGES   800000
#define IN_DIM    128
#define HID       64
#define OUT_DIM   128
#define N_GRAPHS  128

#define NBKT      196        // ceil(50000/256) coarse dst-buckets
#define BSTRIDE   5120       // slots/bucket (mean 4096, 16-sigma margin)
#define CAP       40         // LDS staging depth per bucket (pass A)

// Workspace layout in 4-byte words.
#define OFF_GCUR   0                    // int[196] (zeroed by k_zero)
#define OFF_GSTART 196                  // int[130]
#define OFF_ROWPTR 326                  // int[50001]
#define OFF_SRCL   50328                // ushort[800000] = 400000 words
#define OFF_EPAIRS 450328               // uint[196*5120] = 1,003,520 words
#define OFF_HA     1453848              // __half[3,200,000] = 1.6M words (byte%16==0)
#define OFF_HB     3053848              // __half[3,200,000] = 1.6M words (byte%16==0)
// end = 4,653,848 words = 18.6 MB

// ---------------------------------------------------------------- tiny zero (gcur)
__global__ void k_zero(int* __restrict__ p, int n) {
    const int i = threadIdx.x;
    if (i < n) p[i] = 0;
}

// ---------------------------------------------------------------- helpers
union H8 { float4 f4; __half2 h[4]; };

__device__ inline void acc_h8(float acc[8], const float4 r) {
    const __half2* hp = (const __half2*)&r;
#pragma unroll
    for (int i = 0; i < 4; ++i) {
        const float2 f = __half22float2(hp[i]);
        acc[2 * i]     += f.x;
        acc[2 * i + 1] += f.y;
    }
}

// ================================================================ fused front end
// blocks [0,NBKT): edge bucket scatter    (reads ei; writes gcur/epairs)
// blocks [NBKT,2*NBKT): graph boundaries  (reads batch; writes gstart)
// blocks [2*NBKT, 2*NBKT+782): proj_in    (reads x,W,b; writes hH)
#define S_X 129
#define FRONT_SMEM_BYTES 49408   // max(bucket ~33.7KB, proj 33024+16384)

// Bucket role with COALESCED flushes: work items (bucket,f,base) are recorded
// in an LDS list, then waves copy 16/32 consecutive words per item so lanes
// write consecutive addresses (1-2 64B lines) instead of 64 scattered words.
__device__ __forceinline__ void role_bucket(char* smem, const int* __restrict__ ei,
                                            int* __restrict__ gcur,
                                            unsigned int* __restrict__ epairs,
                                            int bid) {
    int* lcnt    = (int*)smem;               // NBKT
    int* wl_n    = lcnt + NBKT;              // 1
    int* wl_b    = wl_n + 1;                 // 64
    int* wl_f    = wl_b + 64;                // 64
    int* wl_base = wl_f + 64;                // 64
    unsigned int* stage = (unsigned int*)(wl_base + 64);   // NBKT*CAP = 31360B
    const int t = threadIdx.x;
    const int wv = t >> 6, lane = t & 63;
    for (int i = t; i < NBKT; i += 256) lcnt[i] = 0;
    if (t == 0) *wl_n = 0;
    __syncthreads();
    for (int e0 = bid * 256; e0 < N_EDGES; e0 += NBKT * 256) {
        const int e = e0 + t;
        if (e < N_EDGES) {
            const unsigned int src = (unsigned int)ei[e];
            const unsigned int dst = (unsigned int)ei[N_EDGES + e];
            const int b = dst >> 8;
            const unsigned int pk = src | (dst << 16);   // both < 2^16
            const int pos = atomicAdd(&lcnt[b], 1);
            if (pos < CAP) stage[b * CAP + pos] = pk;
            else {  // rare overflow: direct scattered write
                const int gp = atomicAdd(&gcur[b], 1);
                epairs[b * BSTRIDE + gp] = pk;
            }
        }
        __syncthreads();
        // record flush work items
        if (t < NBKT) {
            int n = lcnt[t]; if (n > CAP) n = CAP;
            if (n >= 16) {
                const int f = n & ~15;               // 16 or 32
                const int base = atomicAdd(&gcur[t], f);
                const int w = atomicAdd(wl_n, 1);
                wl_b[w] = t; wl_f[w] = f; wl_base[w] = base;
                lcnt[t] = n - f;
            } else {
                lcnt[t] = n;
            }
        }
        __syncthreads();
        // cooperative coalesced flush: wave per work item
        const int W = *wl_n;
        for (int w = wv; w < W; w += 4) {
            const int b = wl_b[w], f = wl_f[w], base = wl_base[w];
            if (lane < f)
                epairs[b * BSTRIDE + base + lane] = stage[b * CAP + lane];
            // shift remainder to front: dest [0,rem), src [f,f+rem), f>=16>rem
            const int rem = lcnt[b];
            if (lane < rem)
                stage[b * CAP + lane] = stage[b * CAP + f + lane];
        }
        if (t == 0) *wl_n = 0;
        __syncthreads();
    }
    // drain remainders: wave per bucket, coalesced
    for (int b = wv; b < NBKT; b += 4) {
        const int n = lcnt[b];
        if (n > 0) {
            int base = 0;
            if (lane == 0) base = atomicAdd(&gcur[b], n);
            base = __shfl(base, 0, 64);
            if (lane < n)
                epairs[b * BSTRIDE + base + lane] = stage[b * CAP + lane];
        }
    }
}

__device__ __forceinline__ void role_gbound(const int* __restrict__ batch,
                                            int* __restrict__ gstart, int bid) {
    const int n = bid * 256 + threadIdx.x;
    if (n >= N_NODES) return;
    const int b = batch[n];
    if (n == 0) {
        for (int g = 0; g <= b; ++g) gstart[g] = 0;
    } else {
        const int p = batch[n - 1];
        for (int g = p + 1; g <= b; ++g) gstart[g] = n;
    }
    if (n == N_NODES - 1) {
        for (int g = b + 1; g <= N_GRAPHS; ++g) gstart[g] = N_NODES;
    }
}

__device__ __forceinline__ void role_proj(char* smem, const float* __restrict__ x,
                                          const float* __restrict__ W,
                                          const float* __restrict__ b,
                                          __half* __restrict__ hH, int bid) {
    float* A  = (float*)smem;                   // 64*129 floats = 33024 B
    float* Wl = (float*)(smem + 64 * S_X * 4);  // 64*64 floats = 16384 B
    const int t = threadIdx.x;
    const int nb = bid * 64;
    for (int i = t; i < 64 * HID; i += 256) Wl[i] = W[i];   // k = 0..63
    for (int i = t; i < 64 * (IN_DIM / 4); i += 256) {
        const int n = i >> 5;
        const int k4 = (i & 31) * 4;
        float4 val = make_float4(0.f, 0.f, 0.f, 0.f);
        if (nb + n < N_NODES)
            val = *(const float4*)(x + (size_t)(nb + n) * IN_DIM + k4);
        float* dst = &A[n * S_X + k4];
        dst[0] = val.x; dst[1] = val.y; dst[2] = val.z; dst[3] = val.w;
    }
    __syncthreads();

    const int ln = t & 31;
    const int c0 = (t >> 5) * 8;
    float acc[2][8];
#pragma unroll
    for (int j = 0; j < 2; ++j)
#pragma unroll
        for (int c = 0; c < 8; ++c) acc[j][c] = b[c0 + c];
    for (int k = 0; k < 64; ++k) {
        const float a0 = A[ln * S_X + k];
        const float a1 = A[(ln + 32) * S_X + k];
        const float4 wA = *(const float4*)&Wl[k * HID + c0];
        const float4 wB = *(const float4*)&Wl[k * HID + c0 + 4];
        const float w[8] = {wA.x, wA.y, wA.z, wA.w, wB.x, wB.y, wB.z, wB.w};
#pragma unroll
        for (int c = 0; c < 8; ++c) {
            acc[0][c] = fmaf(a0, w[c], acc[0][c]);
            acc[1][c] = fmaf(a1, w[c], acc[1][c]);
        }
    }
    __syncthreads();                                        // Wl half-1 reads done
    for (int i = t; i < 64 * HID; i += 256) Wl[i] = W[64 * HID + i];  // k = 64..127
    __syncthreads();
    for (int k = 64; k < 128; ++k) {
        const float a0 = A[ln * S_X + k];
        const float a1 = A[(ln + 32) * S_X + k];
        const float4 wA = *(const float4*)&Wl[(k - 64) * HID + c0];
        const float4 wB = *(const float4*)&Wl[(k - 64) * HID + c0 + 4];
        const float w[8] = {wA.x, wA.y, wA.z, wA.w, wB.x, wB.y, wB.z, wB.w};
#pragma unroll
        for (int c = 0; c < 8; ++c) {
            acc[0][c] = fmaf(a0, w[c], acc[0][c]);
            acc[1][c] = fmaf(a1, w[c], acc[1][c]);
        }
    }
#pragma unroll
    for (int j = 0; j < 2; ++j) {
        const int n = nb + ln + 32 * j;
        if (n < N_NODES) {
            H8 o;
#pragma unroll
            for (int c = 0; c < 4; ++c)
                o.h[c] = __floats2half2_rn(acc[j][2 * c], acc[j][2 * c + 1]);
            *(float4*)(hH + (size_t)n * HID + c0) = o.f4;
        }
    }
}

__global__ __launch_bounds__(256) void k_front(
        const int* __restrict__ ei, const int* __restrict__ batch,
        const float* __restrict__ x, const float* __restrict__ W,
        const float* __restrict__ b,
        int* __restrict__ gcur, unsigned int* __restrict__ epairs,
        int* __restrict__ gstart, __half* __restrict__ hH) {
    __shared__ __attribute__((aligned(16))) char smem[FRONT_SMEM_BYTES];
    const int bid = blockIdx.x;
    if (bid < NBKT) {
        role_bucket(smem, ei, gcur, epairs, bid);
    } else if (bid < 2 * NBKT) {
        role_gbound(batch, gstart, bid - NBKT);
    } else {
        role_proj(smem, x, W, b, hH, bid - 2 * NBKT);
    }
}

// ---------------------------------------------------------------- pass B: per-bucket CSR in LDS
__global__ __launch_bounds__(256) void k_csr(const int* __restrict__ gcur,
                                             const unsigned int* __restrict__ epairs,
                                             int* __restrict__ rowptr,
                                             unsigned short* __restrict__ srclist) {
    __shared__ int lhist[256];
    __shared__ int lcur[256];
    __shared__ int lsrc[BSTRIDE];     // 20.5 KB
    __shared__ int pws[4], wtot[4];
    const int b = blockIdx.x;
    const int t = threadIdx.x;
    const int lane = t & 63, wv = t >> 6;

    int po = 0;
    for (int j = t; j < b; j += 256) po += gcur[j];
#pragma unroll
    for (int m = 32; m; m >>= 1) po += __shfl_xor(po, m, 64);
    if (lane == 0) pws[wv] = po;
    lhist[t] = 0;
    __syncthreads();
    const int base = pws[0] + pws[1] + pws[2] + pws[3];
    const int cnt = gcur[b];

    for (int i = t; i < cnt; i += 256)
        atomicAdd(&lhist[(epairs[b * BSTRIDE + i] >> 16) & 255], 1);
    __syncthreads();

    const int d = lhist[t];
    int incl = d;
#pragma unroll
    for (int off = 1; off < 64; off <<= 1) {
        const int u = __shfl_up(incl, off, 64);
        if (lane >= off) incl += u;
    }
    if (lane == 63) wtot[wv] = incl;
    __syncthreads();
    int woff = 0;
#pragma unroll
    for (int i = 0; i < 4; ++i) woff += (i < wv) ? wtot[i] : 0;
    const int excl = woff + incl - d;
    lcur[t] = excl;
    const int node = b * 256 + t;
    if (node < N_NODES) rowptr[node] = base + excl;
    if (b == NBKT - 1 && t == 0) rowptr[N_NODES] = base + cnt;  // == N_EDGES
    __syncthreads();

    for (int i = t; i < cnt; i += 256) {
        const unsigned int u = epairs[b * BSTRIDE + i];
        const int pos = atomicAdd(&lcur[(u >> 16) & 255], 1);
        lsrc[pos] = (int)(u & 0xFFFFu);
    }
    __syncthreads();
    for (int i = t; i < cnt; i += 256)
        srclist[base + i] = (unsigned short)lsrc[i];
}

// ---------------------------------------------------------------- fused conv: gather + 2-layer MLP
// 64-node tile -> 782 blocks; LDS 32.6 KB -> 4 blocks/CU ceiling.
#define S_A 65
__global__ __launch_bounds__(256, 4) void k_conv(
        const __half* __restrict__ hin,
        const int* __restrict__ rowptr, const unsigned short* __restrict__ srclist,
        const float* __restrict__ W1, const float* __restrict__ b1,
        const float* __restrict__ W2, const float* __restrict__ b2,
        __half* __restrict__ hout) {
    __shared__ float A[64 * S_A];      // 16.6 KB (v, then u)
    __shared__ float Wl[HID * HID];    // 16 KB (W1, then W2)
    const int t = threadIdx.x;
    for (int i = t; i < HID * HID; i += 256) Wl[i] = W1[i];

    const int nb = blockIdx.x * 64;
    const int grp = t >> 3;            // 0..31: node within pass
    const int q = t & 7;               // 8-half chunk of the row
#pragma unroll
    for (int pass = 0; pass < 2; ++pass) {
        const int nloc = pass * 32 + grp;
        const int node = nb + nloc;
        float acc[8] = {0.f, 0.f, 0.f, 0.f, 0.f, 0.f, 0.f, 0.f};
        if (node < N_NODES) {
            acc_h8(acc, *(const float4*)(hin + (size_t)node * HID + q * 8));  // self
            const int beg = rowptr[node];
            const int end = rowptr[node + 1];
            int e = beg;
            for (; e + 8 <= end; e += 8) {
                int s[8];
#pragma unroll
                for (int i = 0; i < 8; ++i) s[i] = srclist[e + i];
                float4 r[8];
#pragma unroll
                for (int i = 0; i < 8; ++i)
                    r[i] = *(const float4*)(hin + (size_t)s[i] * HID + q * 8);
#pragma unroll
                for (int i = 0; i < 8; ++i) acc_h8(acc, r[i]);
            }
            for (; e < end; ++e)
                acc_h8(acc, *(const float4*)(hin + (size_t)srclist[e] * HID + q * 8));
        }
        float* dst = &A[nloc * S_A + q * 8];
#pragma unroll
        for (int i = 0; i < 8; ++i) dst[i] = acc[i];
    }
    __syncthreads();

    const int ln = t & 31;
    const int c0 = (t >> 5) * 8;
    float bb[8];
#pragma unroll
    for (int c = 0; c < 8; ++c) bb[c] = b1[c0 + c];

    float acc2[2][8];
    // ---- layer 1
#pragma unroll
    for (int j = 0; j < 2; ++j)
#pragma unroll
        for (int c = 0; c < 8; ++c) acc2[j][c] = bb[c];
    for (int k = 0; k < HID; ++k) {
        const float a0 = A[ln * S_A + k];
        const float a1 = A[(ln + 32) * S_A + k];
        const float4 wA = *(const float4*)&Wl[k * HID + c0];
        const float4 wB = *(const float4*)&Wl[k * HID + c0 + 4];
        const float w[8] = {wA.x, wA.y, wA.z, wA.w, wB.x, wB.y, wB.z, wB.w};
#pragma unroll
        for (int c = 0; c < 8; ++c) {
            acc2[0][c] = fmaf(a0, w[c], acc2[0][c]);
            acc2[1][c] = fmaf(a1, w[c], acc2[1][c]);
        }
    }
    __syncthreads();   // all layer-1 A and Wl reads complete
    // write u = relu(acc2) into A; stage W2 into Wl
#pragma unroll
    for (int j = 0; j < 2; ++j) {
        float* dst = &A[(ln + 32 * j) * S_A + c0];
#pragma unroll
        for (int c = 0; c < 8; ++c) dst[c] = fmaxf(acc2[j][c], 0.0f);
    }
    for (int i = t; i < HID * HID; i += 256) Wl[i] = W2[i];
#pragma unroll
    for (int c = 0; c < 8; ++c) bb[c] = b2[c0 + c];
    __syncthreads();

    // ---- layer 2
#pragma unroll
    for (int j = 0; j < 2; ++j)
#pragma unroll
        for (int c = 0; c < 8; ++c) acc2[j][c] = bb[c];
    for (int k = 0; k < HID; ++k) {
        const float a0 = A[ln * S_A + k];
        const float a1 = A[(ln + 32) * S_A + k];
        const float4 wA = *(const float4*)&Wl[k * HID + c0];
        const float4 wB = *(const float4*)&Wl[k * HID + c0 + 4];
        const float w[8] = {wA.x, wA.y, wA.z, wA.w, wB.x, wB.y, wB.z, wB.w};
#pragma unroll
        for (int c = 0; c < 8; ++c) {
            acc2[0][c] = fmaf(a0, w[c], acc2[0][c]);
            acc2[1][c] = fmaf(a1, w[c], acc2[1][c]);
        }
    }
#pragma unroll
    for (int j = 0; j < 2; ++j) {
        const int n = nb + ln + 32 * j;
        if (n < N_NODES) {
            H8 o;
#pragma unroll
            for (int c = 0; c < 4; ++c)
                o.h[c] = __floats2half2_rn(fmaxf(acc2[j][2 * c], 0.f),
                                           fmaxf(acc2[j][2 * c + 1], 0.f));
            *(float4*)(hout + (size_t)n * HID + c0) = o.f4;
        }
    }
}

// ---------------------------------------------------------------- fused mean-pool + proj_out
__global__ __launch_bounds__(256) void k_poolout(
        const __half* __restrict__ hin, const int* __restrict__ gstart,
        const float* __restrict__ Wo, const float* __restrict__ bo,
        float* __restrict__ out) {
    __shared__ float Wl[HID * OUT_DIM];   // 32 KB
    __shared__ float red[4][HID];
    __shared__ float mean[HID];
    const int g = blockIdx.x;
    const int t = threadIdx.x;
    for (int i = t; i < HID * OUT_DIM; i += 256) Wl[i] = Wo[i];
    const int c = t & 63;
    const int wv = t >> 6;
    const int beg = gstart[g], end = gstart[g + 1];
    float acc = 0.0f;
    for (int n = beg + wv; n < end; n += 4)
        acc += __half2float(hin[(size_t)n * HID + c]);
    red[wv][c] = acc;
    __syncthreads();
    if (t < HID) {
        const float cnt = (float)(end - beg);
        mean[t] = cnt > 0.0f ? (red[0][t] + red[1][t] + red[2][t] + red[3][t]) / cnt
                             : 0.0f;
    }
    __syncthreads();
    if (t < OUT_DIM) {
        float o = 0.0f;
        for (int k = 0; k < HID; ++k)
            o = fmaf(mean[k], Wl[k * OUT_DIM + t], o);
        out[g * OUT_DIM + t] = (end > beg) ? o + bo[t] : 0.0f;
    }
}

// ---------------------------------------------------------------- launch
extern "C" void kernel_launch(void* const* d_in, const int* in_sizes, int n_in,
                              void* d_out, int out_size, void* d_ws, size_t ws_size,
                              hipStream_t stream) {
    const float* x     = (const float*)d_in[0];
    const int*   ei    = (const int*)d_in[1];
    const int*   batch = (const int*)d_in[2];
    const float* W_in  = (const float*)d_in[3];
    const float* b_in  = (const float*)d_in[4];
    const float* W1_0  = (const float*)d_in[5];
    const float* b1_0  = (const float*)d_in[6];
    const float* W2_0  = (const float*)d_in[7];
    const float* b2_0  = (const float*)d_in[8];
    const float* W1_1  = (const float*)d_in[9];
    const float* b1_1  = (const float*)d_in[10];
    const float* W2_1  = (const float*)d_in[11];
    const float* b2_1  = (const float*)d_in[12];
    const float* W_out = (const float*)d_in[13];
    const float* b_out = (const float*)d_in[14];
    float* out = (float*)d_out;

    unsigned int*   wsw    = (unsigned int*)d_ws;
    int*            gcur   = (int*)(wsw + OFF_GCUR);
    int*            gstart = (int*)(wsw + OFF_GSTART);
    int*            rowptr = (int*)(wsw + OFF_ROWPTR);
    unsigned short* srcl   = (unsigned short*)(wsw + OFF_SRCL);
    unsigned int*   epairs = (unsigned int*)(wsw + OFF_EPAIRS);
    __half*         hA     = (__half*)(wsw + OFF_HA);
    __half*         hB     = (__half*)(wsw + OFF_HB);

    const int pi_blocks = (N_NODES + 63) / 64;        // 782
    const int cv_blocks = (N_NODES + 63) / 64;        // 782
    const int front_blocks = 2 * NBKT + pi_blocks;    // 1174

    k_zero<<<1, 256, 0, stream>>>(gcur, NBKT);
    k_front<<<front_blocks, 256, 0, stream>>>(ei, batch, x, W_in, b_in,
                                              gcur, epairs, gstart, hA);
    k_csr<<<NBKT, 256, 0, stream>>>(gcur, epairs, rowptr, srcl);
    k_conv<<<cv_blocks, 256, 0, stream>>>(hA, rowptr, srcl, W1_0, b1_0, W2_0, b2_0, hB);
    k_conv<<<cv_blocks, 256, 0, stream>>>(hB, rowptr, srcl, W1_1, b1_1, W2_1, b2_1, hA);
    k_poolout<<<N_GRAPHS, 256, 0, stream>>>(hA, gstart, W_out, b_out, out);
}

// Round 11
// 250.978 us; speedup vs baseline: 1.5560x; 1.5560x over previous
//
#include <hip/hip_runtime.h>
#include <hip/hip_fp16.h>

// Problem constants (fixed by the reference)
#define N_NODES   50000
#define N_EDGES   800000
#define IN_DIM    128
#define HID       64
#define OUT_DIM   128
#define N_GRAPHS  128

#define NBKT      196        // ceil(50000/256) coarse dst-buckets
#define BSTRIDE   5120       // slots/bucket (mean 4096, 16-sigma margin)
#define CAP       40         // LDS staging depth per bucket (pass A)

// Workspace layout in 4-byte words.
#define OFF_GCUR   0                    // int[196] (zeroed by k_zero)
#define OFF_GSTART 196                  // int[130]
#define OFF_ROWPTR 326                  // int[50001]
#define OFF_SRCL   50328                // ushort[800000] = 400000 words
#define OFF_EPAIRS 450328               // uint[196*5120] = 1,003,520 words
#define OFF_HA     1453848              // __half[3,200,000] = 1.6M words (byte%16==0)
#define OFF_HB     3053848              // __half[3,200,000] = 1.6M words (byte%16==0)
// end = 4,653,848 words = 18.6 MB

// ---------------------------------------------------------------- tiny zero (gcur)
__global__ void k_zero(int* __restrict__ p, int n) {
    const int i = threadIdx.x;
    if (i < n) p[i] = 0;
}

// ---------------------------------------------------------------- helpers
union H8 { float4 f4; __half2 h[4]; };

__device__ inline void acc_h8(float acc[8], const float4 r) {
    const __half2* hp = (const __half2*)&r;
#pragma unroll
    for (int i = 0; i < 4; ++i) {
        const float2 f = __half22float2(hp[i]);
        acc[2 * i]     += f.x;
        acc[2 * i + 1] += f.y;
    }
}

// ================================================================ fused front end
// blocks [0,NBKT): edge bucket scatter    (reads ei; writes gcur/epairs)
// blocks [NBKT,2*NBKT): graph boundaries  (reads batch; writes gstart)
// blocks [2*NBKT, 2*NBKT+782): proj_in    (reads x,W,b; writes hH)
#define S_X 129
#define FRONT_SMEM_BYTES 49408   // max(bucket 32144, proj 33024+16384)

// R9-style per-thread flush (196-thread parallel, fire-and-forget stores),
// widened to uint4: 16B per store -> 1/4 the scattered transactions.
__device__ __forceinline__ void role_bucket(char* smem, const int* __restrict__ ei,
                                            int* __restrict__ gcur,
                                            unsigned int* __restrict__ epairs,
                                            int bid) {
    int* lcnt = (int*)smem;                                 // NBKT words
    unsigned int* stage = (unsigned int*)(smem + NBKT * 4); // NBKT*CAP words
    const int t = threadIdx.x;
    for (int i = t; i < NBKT; i += 256) lcnt[i] = 0;
    __syncthreads();
    for (int e0 = bid * 256; e0 < N_EDGES; e0 += NBKT * 256) {
        const int e = e0 + t;
        if (e < N_EDGES) {
            const unsigned int src = (unsigned int)ei[e];
            const unsigned int dst = (unsigned int)ei[N_EDGES + e];
            const int b = dst >> 8;
            const unsigned int pk = src | (dst << 16);   // both < 2^16
            const int pos = atomicAdd(&lcnt[b], 1);
            if (pos < CAP) stage[b * CAP + pos] = pk;
            else {  // astronomically rare overflow: direct scattered write
                const int gp = atomicAdd(&gcur[b], 1);
                epairs[b * BSTRIDE + gp] = pk;
            }
        }
        __syncthreads();
        if (t < NBKT) {
            int n = lcnt[t]; if (n > CAP) n = CAP;
            if (n >= 16) {
                const int f = n & ~15;               // 16 or 32
                const int base = atomicAdd(&gcur[t], f);
                if ((base & 3) == 0) {               // 16B-aligned (always, unless overflow hit)
                    for (int i = 0; i < f; i += 4)
                        *(uint4*)&epairs[t * BSTRIDE + base + i] =
                            *(const uint4*)&stage[t * CAP + i];
                } else {                             // scalar fallback
                    for (int i = 0; i < f; ++i)
                        epairs[t * BSTRIDE + base + i] = stage[t * CAP + i];
                }
                for (int i = 0; i < n - f; ++i)      // move remainder to front
                    stage[t * CAP + i] = stage[t * CAP + f + i];
                lcnt[t] = n - f;
            } else {
                lcnt[t] = n;
            }
        }
        __syncthreads();
    }
    // drain remainders (<16 words each; once)
    if (t < NBKT) {
        const int n = lcnt[t];
        if (n > 0) {
            const int base = atomicAdd(&gcur[t], n);
            for (int i = 0; i < n; ++i)
                epairs[t * BSTRIDE + base + i] = stage[t * CAP + i];
        }
    }
}

__device__ __forceinline__ void role_gbound(const int* __restrict__ batch,
                                            int* __restrict__ gstart, int bid) {
    const int n = bid * 256 + threadIdx.x;
    if (n >= N_NODES) return;
    const int b = batch[n];
    if (n == 0) {
        for (int g = 0; g <= b; ++g) gstart[g] = 0;
    } else {
        const int p = batch[n - 1];
        for (int g = p + 1; g <= b; ++g) gstart[g] = n;
    }
    if (n == N_NODES - 1) {
        for (int g = b + 1; g <= N_GRAPHS; ++g) gstart[g] = N_NODES;
    }
}

__device__ __forceinline__ void role_proj(char* smem, const float* __restrict__ x,
                                          const float* __restrict__ W,
                                          const float* __restrict__ b,
                                          __half* __restrict__ hH, int bid) {
    float* A  = (float*)smem;                   // 64*129 floats = 33024 B
    float* Wl = (float*)(smem + 64 * S_X * 4);  // 64*64 floats = 16384 B
    const int t = threadIdx.x;
    const int nb = bid * 64;
    for (int i = t; i < 64 * HID; i += 256) Wl[i] = W[i];   // k = 0..63
    for (int i = t; i < 64 * (IN_DIM / 4); i += 256) {
        const int n = i >> 5;
        const int k4 = (i & 31) * 4;
        float4 val = make_float4(0.f, 0.f, 0.f, 0.f);
        if (nb + n < N_NODES)
            val = *(const float4*)(x + (size_t)(nb + n) * IN_DIM + k4);
        float* dst = &A[n * S_X + k4];
        dst[0] = val.x; dst[1] = val.y; dst[2] = val.z; dst[3] = val.w;
    }
    __syncthreads();

    const int ln = t & 31;
    const int c0 = (t >> 5) * 8;
    float acc[2][8];
#pragma unroll
    for (int j = 0; j < 2; ++j)
#pragma unroll
        for (int c = 0; c < 8; ++c) acc[j][c] = b[c0 + c];
    for (int k = 0; k < 64; ++k) {
        const float a0 = A[ln * S_X + k];
        const float a1 = A[(ln + 32) * S_X + k];
        const float4 wA = *(const float4*)&Wl[k * HID + c0];
        const float4 wB = *(const float4*)&Wl[k * HID + c0 + 4];
        const float w[8] = {wA.x, wA.y, wA.z, wA.w, wB.x, wB.y, wB.z, wB.w};
#pragma unroll
        for (int c = 0; c < 8; ++c) {
            acc[0][c] = fmaf(a0, w[c], acc[0][c]);
            acc[1][c] = fmaf(a1, w[c], acc[1][c]);
        }
    }
    __syncthreads();                                        // Wl half-1 reads done
    for (int i = t; i < 64 * HID; i += 256) Wl[i] = W[64 * HID + i];  // k = 64..127
    __syncthreads();
    for (int k = 64; k < 128; ++k) {
        const float a0 = A[ln * S_X + k];
        const float a1 = A[(ln + 32) * S_X + k];
        const float4 wA = *(const float4*)&Wl[(k - 64) * HID + c0];
        const float4 wB = *(const float4*)&Wl[(k - 64) * HID + c0 + 4];
        const float w[8] = {wA.x, wA.y, wA.z, wA.w, wB.x, wB.y, wB.z, wB.w};
#pragma unroll
        for (int c = 0; c < 8; ++c) {
            acc[0][c] = fmaf(a0, w[c], acc[0][c]);
            acc[1][c] = fmaf(a1, w[c], acc[1][c]);
        }
    }
#pragma unroll
    for (int j = 0; j < 2; ++j) {
        const int n = nb + ln + 32 * j;
        if (n < N_NODES) {
            H8 o;
#pragma unroll
            for (int c = 0; c < 4; ++c)
                o.h[c] = __floats2half2_rn(acc[j][2 * c], acc[j][2 * c + 1]);
            *(float4*)(hH + (size_t)n * HID + c0) = o.f4;
        }
    }
}

__global__ __launch_bounds__(256) void k_front(
        const int* __restrict__ ei, const int* __restrict__ batch,
        const float* __restrict__ x, const float* __restrict__ W,
        const float* __restrict__ b,
        int* __restrict__ gcur, unsigned int* __restrict__ epairs,
        int* __restrict__ gstart, __half* __restrict__ hH) {
    __shared__ __attribute__((aligned(16))) char smem[FRONT_SMEM_BYTES];
    const int bid = blockIdx.x;
    if (bid < NBKT) {
        role_bucket(smem, ei, gcur, epairs, bid);
    } else if (bid < 2 * NBKT) {
        role_gbound(batch, gstart, bid - NBKT);
    } else {
        role_proj(smem, x, W, b, hH, bid - 2 * NBKT);
    }
}

// ---------------------------------------------------------------- pass B: per-bucket CSR in LDS
__global__ __launch_bounds__(256) void k_csr(const int* __restrict__ gcur,
                                             const unsigned int* __restrict__ epairs,
                                             int* __restrict__ rowptr,
                                             unsigned short* __restrict__ srclist) {
    __shared__ int lhist[256];
    __shared__ int lcur[256];
    __shared__ int lsrc[BSTRIDE];     // 20.5 KB
    __shared__ int pws[4], wtot[4];
    const int b = blockIdx.x;
    const int t = threadIdx.x;
    const int lane = t & 63, wv = t >> 6;

    int po = 0;
    for (int j = t; j < b; j += 256) po += gcur[j];
#pragma unroll
    for (int m = 32; m; m >>= 1) po += __shfl_xor(po, m, 64);
    if (lane == 0) pws[wv] = po;
    lhist[t] = 0;
    __syncthreads();
    const int base = pws[0] + pws[1] + pws[2] + pws[3];
    const int cnt = gcur[b];

    for (int i = t; i < cnt; i += 256)
        atomicAdd(&lhist[(epairs[b * BSTRIDE + i] >> 16) & 255], 1);
    __syncthreads();

    const int d = lhist[t];
    int incl = d;
#pragma unroll
    for (int off = 1; off < 64; off <<= 1) {
        const int u = __shfl_up(incl, off, 64);
        if (lane >= off) incl += u;
    }
    if (lane == 63) wtot[wv] = incl;
    __syncthreads();
    int woff = 0;
#pragma unroll
    for (int i = 0; i < 4; ++i) woff += (i < wv) ? wtot[i] : 0;
    const int excl = woff + incl - d;
    lcur[t] = excl;
    const int node = b * 256 + t;
    if (node < N_NODES) rowptr[node] = base + excl;
    if (b == NBKT - 1 && t == 0) rowptr[N_NODES] = base + cnt;  // == N_EDGES
    __syncthreads();

    for (int i = t; i < cnt; i += 256) {
        const unsigned int u = epairs[b * BSTRIDE + i];
        const int pos = atomicAdd(&lcur[(u >> 16) & 255], 1);
        lsrc[pos] = (int)(u & 0xFFFFu);
    }
    __syncthreads();
    for (int i = t; i < cnt; i += 256)
        srclist[base + i] = (unsigned short)lsrc[i];
}

// ---------------------------------------------------------------- fused conv: gather + 2-layer MLP
// 64-node tile -> 782 blocks; LDS 32.6 KB -> 4 blocks/CU ceiling.
#define S_A 65
__global__ __launch_bounds__(256, 4) void k_conv(
        const __half* __restrict__ hin,
        const int* __restrict__ rowptr, const unsigned short* __restrict__ srclist,
        const float* __restrict__ W1, const float* __restrict__ b1,
        const float* __restrict__ W2, const float* __restrict__ b2,
        __half* __restrict__ hout) {
    __shared__ float A[64 * S_A];      // 16.6 KB (v, then u)
    __shared__ float Wl[HID * HID];    // 16 KB (W1, then W2)
    const int t = threadIdx.x;
    for (int i = t; i < HID * HID; i += 256) Wl[i] = W1[i];

    const int nb = blockIdx.x * 64;
    const int grp = t >> 3;            // 0..31: node within pass
    const int q = t & 7;               // 8-half chunk of the row
#pragma unroll
    for (int pass = 0; pass < 2; ++pass) {
        const int nloc = pass * 32 + grp;
        const int node = nb + nloc;
        float acc[8] = {0.f, 0.f, 0.f, 0.f, 0.f, 0.f, 0.f, 0.f};
        if (node < N_NODES) {
            acc_h8(acc, *(const float4*)(hin + (size_t)node * HID + q * 8));  // self
            const int beg = rowptr[node];
            const int end = rowptr[node + 1];
            int e = beg;
            for (; e + 8 <= end; e += 8) {
                int s[8];
#pragma unroll
                for (int i = 0; i < 8; ++i) s[i] = srclist[e + i];
                float4 r[8];
#pragma unroll
                for (int i = 0; i < 8; ++i)
                    r[i] = *(const float4*)(hin + (size_t)s[i] * HID + q * 8);
#pragma unroll
                for (int i = 0; i < 8; ++i) acc_h8(acc, r[i]);
            }
            for (; e < end; ++e)
                acc_h8(acc, *(const float4*)(hin + (size_t)srclist[e] * HID + q * 8));
        }
        float* dst = &A[nloc * S_A + q * 8];
#pragma unroll
        for (int i = 0; i < 8; ++i) dst[i] = acc[i];
    }
    __syncthreads();

    const int ln = t & 31;
    const int c0 = (t >> 5) * 8;
    float bb[8];
#pragma unroll
    for (int c = 0; c < 8; ++c) bb[c] = b1[c0 + c];

    float acc2[2][8];
    // ---- layer 1
#pragma unroll
    for (int j = 0; j < 2; ++j)
#pragma unroll
        for (int c = 0; c < 8; ++c) acc2[j][c] = bb[c];
    for (int k = 0; k < HID; ++k) {
        const float a0 = A[ln * S_A + k];
        const float a1 = A[(ln + 32) * S_A + k];
        const float4 wA = *(const float4*)&Wl[k * HID + c0];
        const float4 wB = *(const float4*)&Wl[k * HID + c0 + 4];
        const float w[8] = {wA.x, wA.y, wA.z, wA.w, wB.x, wB.y, wB.z, wB.w};
#pragma unroll
        for (int c = 0; c < 8; ++c) {
            acc2[0][c] = fmaf(a0, w[c], acc2[0][c]);
            acc2[1][c] = fmaf(a1, w[c], acc2[1][c]);
        }
    }
    __syncthreads();   // all layer-1 A and Wl reads complete
    // write u = relu(acc2) into A; stage W2 into Wl
#pragma unroll
    for (int j = 0; j < 2; ++j) {
        float* dst = &A[(ln + 32 * j) * S_A + c0];
#pragma unroll
        for (int c = 0; c < 8; ++c) dst[c] = fmaxf(acc2[j][c], 0.0f);
    }
    for (int i = t; i < HID * HID; i += 256) Wl[i] = W2[i];
#pragma unroll
    for (int c = 0; c < 8; ++c) bb[c] = b2[c0 + c];
    __syncthreads();

    // ---- layer 2
#pragma unroll
    for (int j = 0; j < 2; ++j)
#pragma unroll
        for (int c = 0; c < 8; ++c) acc2[j][c] = bb[c];
    for (int k = 0; k < HID; ++k) {
        const float a0 = A[ln * S_A + k];
        const float a1 = A[(ln + 32) * S_A + k];
        const float4 wA = *(const float4*)&Wl[k * HID + c0];
        const float4 wB = *(const float4*)&Wl[k * HID + c0 + 4];
        const float w[8] = {wA.x, wA.y, wA.z, wA.w, wB.x, wB.y, wB.z, wB.w};
#pragma unroll
        for (int c = 0; c < 8; ++c) {
            acc2[0][c] = fmaf(a0, w[c], acc2[0][c]);
            acc2[1][c] = fmaf(a1, w[c], acc2[1][c]);
        }
    }
#pragma unroll
    for (int j = 0; j < 2; ++j) {
        const int n = nb + ln + 32 * j;
        if (n < N_NODES) {
            H8 o;
#pragma unroll
            for (int c = 0; c < 4; ++c)
                o.h[c] = __floats2half2_rn(fmaxf(acc2[j][2 * c], 0.f),
                                           fmaxf(acc2[j][2 * c + 1], 0.f));
            *(float4*)(hout + (size_t)n * HID + c0) = o.f4;
        }
    }
}

// ---------------------------------------------------------------- fused mean-pool + proj_out
__global__ __launch_bounds__(256) void k_poolout(
        const __half* __restrict__ hin, const int* __restrict__ gstart,
        const float* __restrict__ Wo, const float* __restrict__ bo,
        float* __restrict__ out) {
    __shared__ float Wl[HID * OUT_DIM];   // 32 KB
    __shared__ float red[4][HID];
    __shared__ float mean[HID];
    const int g = blockIdx.x;
    const int t = threadIdx.x;
    for (int i = t; i < HID * OUT_DIM; i += 256) Wl[i] = Wo[i];
    const int c = t & 63;
    const int wv = t >> 6;
    const int beg = gstart[g], end = gstart[g + 1];
    float acc = 0.0f;
    for (int n = beg + wv; n < end; n += 4)
        acc += __half2float(hin[(size_t)n * HID + c]);
    red[wv][c] = acc;
    __syncthreads();
    if (t < HID) {
        const float cnt = (float)(end - beg);
        mean[t] = cnt > 0.0f ? (red[0][t] + red[1][t] + red[2][t] + red[3][t]) / cnt
                             : 0.0f;
    }
    __syncthreads();
    if (t < OUT_DIM) {
        float o = 0.0f;
        for (int k = 0; k < HID; ++k)
            o = fmaf(mean[k], Wl[k * OUT_DIM + t], o);
        out[g * OUT_DIM + t] = (end > beg) ? o + bo[t] : 0.0f;
    }
}

// ---------------------------------------------------------------- launch
extern "C" void kernel_launch(void* const* d_in, const int* in_sizes, int n_in,
                              void* d_out, int out_size, void* d_ws, size_t ws_size,
                              hipStream_t stream) {
    const float* x     = (const float*)d_in[0];
    const int*   ei    = (const int*)d_in[1];
    const int*   batch = (const int*)d_in[2];
    const float* W_in  = (const float*)d_in[3];
    const float* b_in  = (const float*)d_in[4];
    const float* W1_0  = (const float*)d_in[5];
    const float* b1_0  = (const float*)d_in[6];
    const float* W2_0  = (const float*)d_in[7];
    const float* b2_0  = (const float*)d_in[8];
    const float* W1_1  = (const float*)d_in[9];
    const float* b1_1  = (const float*)d_in[10];
    const float* W2_1  = (const float*)d_in[11];
    const float* b2_1  = (const float*)d_in[12];
    const float* W_out = (const float*)d_in[13];
    const float* b_out = (const float*)d_in[14];
    float* out = (float*)d_out;

    unsigned int*   wsw    = (unsigned int*)d_ws;
    int*            gcur   = (int*)(wsw + OFF_GCUR);
    int*            gstart = (int*)(wsw + OFF_GSTART);
    int*            rowptr = (int*)(wsw + OFF_ROWPTR);
    unsigned short* srcl   = (unsigned short*)(wsw + OFF_SRCL);
    unsigned int*   epairs = (unsigned int*)(wsw + OFF_EPAIRS);
    __half*         hA     = (__half*)(wsw + OFF_HA);
    __half*         hB     = (__half*)(wsw + OFF_HB);

    const int pi_blocks = (N_NODES + 63) / 64;        // 782
    const int cv_blocks = (N_NODES + 63) / 64;        // 782
    const int front_blocks = 2 * NBKT + pi_blocks;    // 1174

    k_zero<<<1, 256, 0, stream>>>(gcur, NBKT);
    k_front<<<front_blocks, 256, 0, stream>>>(ei, batch, x, W_in, b_in,
                                              gcur, epairs, gstart, hA);
    k_csr<<<NBKT, 256, 0, stream>>>(gcur, epairs, rowptr, srcl);
    k_conv<<<cv_blocks, 256, 0, stream>>>(hA, rowptr, srcl, W1_0, b1_0, W2_0, b2_0, hB);
    k_conv<<<cv_blocks, 256, 0, stream>>>(hB, rowptr, srcl, W1_1, b1_1, W2_1, b2_1, hA);
    k_poolout<<<N_GRAPHS, 256, 0, stream>>>(hA, gstart, W_out, b_out, out);
}

// Round 12
// 244.072 us; speedup vs baseline: 1.6000x; 1.0283x over previous
//
#include <hip/hip_runtime.h>
#include <hip/hip_fp16.h>

// Problem constants (fixed by the reference)
#define N_NODES   50000
#define N_EDGES   800000
#define IN_DIM    128
#define HID       64
#define OUT_DIM   128
#define N_GRAPHS  128

#define NBKT      196        // ceil(50000/256) coarse dst-buckets
#define BBLK      (2*NBKT)   // bucket-role blocks (392): 4 serial iterations each
#define BSTRIDE   5120       // slots/bucket (mean 4096, 16-sigma margin)
#define CAP       40         // LDS staging depth per bucket (pass A)

// Workspace layout in 4-byte words.
#define OFF_GCUR   0                    // int[196] (zeroed by k_zero)
#define OFF_GSTART 196                  // int[130]
#define OFF_ROWPTR 326                  // int[50001]
#define OFF_SRCL   50328                // ushort[800000] = 400000 words
#define OFF_EPAIRS 450328               // uint[196*5120] = 1,003,520 words
#define OFF_HA     1453848              // __half[3,200,000] = 1.6M words (byte%16==0)
#define OFF_HB     3053848              // __half[3,200,000] = 1.6M words (byte%16==0)
// end = 4,653,848 words = 18.6 MB

// ---------------------------------------------------------------- tiny zero (gcur)
__global__ void k_zero(int* __restrict__ p, int n) {
    const int i = threadIdx.x;
    if (i < n) p[i] = 0;
}

// ---------------------------------------------------------------- helpers
union H8 { float4 f4; __half2 h[4]; };

__device__ inline void acc_h8(float acc[8], const float4 r) {
    const __half2* hp = (const __half2*)&r;
#pragma unroll
    for (int i = 0; i < 4; ++i) {
        const float2 f = __half22float2(hp[i]);
        acc[2 * i]     += f.x;
        acc[2 * i + 1] += f.y;
    }
}

// ================================================================ fused front end
// blocks [0,BBLK): edge bucket scatter        (reads ei; writes gcur/epairs)
// blocks [BBLK,BBLK+NBKT): graph boundaries   (reads batch; writes gstart)
// blocks [BBLK+NBKT, +782): proj_in           (reads x,W,b; writes hH)
#define S_X 129
#define FRONT_SMEM_BYTES 49408   // max(bucket 32144, proj 33024+16384)

// R9-proven per-thread flush; 392 blocks x 512-edge chunks -> 4 serial
// iterations per block (was 16) to cut the sync-coupled latency chain.
__device__ __forceinline__ void role_bucket(char* smem, const int* __restrict__ ei,
                                            int* __restrict__ gcur,
                                            unsigned int* __restrict__ epairs,
                                            int bid) {
    int* lcnt = (int*)smem;                                 // NBKT words
    unsigned int* stage = (unsigned int*)(smem + NBKT * 4); // NBKT*CAP words
    const int t = threadIdx.x;
    for (int i = t; i < NBKT; i += 256) lcnt[i] = 0;
    __syncthreads();
    for (int e0 = bid * 512; e0 < N_EDGES; e0 += BBLK * 512) {
#pragma unroll
        for (int half = 0; half < 2; ++half) {
            const int e = e0 + half * 256 + t;
            if (e < N_EDGES) {
                const unsigned int src = (unsigned int)ei[e];
                const unsigned int dst = (unsigned int)ei[N_EDGES + e];
                const int b = dst >> 8;
                const unsigned int pk = src | (dst << 16);   // both < 2^16
                const int pos = atomicAdd(&lcnt[b], 1);
                if (pos < CAP) stage[b * CAP + pos] = pk;
                else {  // astronomically rare overflow: direct scattered write
                    const int gp = atomicAdd(&gcur[b], 1);
                    epairs[b * BSTRIDE + gp] = pk;
                }
            }
        }
        __syncthreads();
        if (t < NBKT) {
            int n = lcnt[t]; if (n > CAP) n = CAP;
            if (n >= 16) {
                const int f = n & ~15;               // 16 or 32
                const int base = atomicAdd(&gcur[t], f);
                if ((base & 3) == 0) {               // 16B-aligned (always, unless overflow hit)
                    for (int i = 0; i < f; i += 4)
                        *(uint4*)&epairs[t * BSTRIDE + base + i] =
                            *(const uint4*)&stage[t * CAP + i];
                } else {                             // scalar fallback
                    for (int i = 0; i < f; ++i)
                        epairs[t * BSTRIDE + base + i] = stage[t * CAP + i];
                }
                for (int i = 0; i < n - f; ++i)      // move remainder to front
                    stage[t * CAP + i] = stage[t * CAP + f + i];
                lcnt[t] = n - f;
            } else {
                lcnt[t] = n;
            }
        }
        __syncthreads();
    }
    // drain remainders (<16 words each; once)
    if (t < NBKT) {
        const int n = lcnt[t];
        if (n > 0) {
            const int base = atomicAdd(&gcur[t], n);
            for (int i = 0; i < n; ++i)
                epairs[t * BSTRIDE + base + i] = stage[t * CAP + i];
        }
    }
}

__device__ __forceinline__ void role_gbound(const int* __restrict__ batch,
                                            int* __restrict__ gstart, int bid) {
    const int n = bid * 256 + threadIdx.x;
    if (n >= N_NODES) return;
    const int b = batch[n];
    if (n == 0) {
        for (int g = 0; g <= b; ++g) gstart[g] = 0;
    } else {
        const int p = batch[n - 1];
        for (int g = p + 1; g <= b; ++g) gstart[g] = n;
    }
    if (n == N_NODES - 1) {
        for (int g = b + 1; g <= N_GRAPHS; ++g) gstart[g] = N_NODES;
    }
}

__device__ __forceinline__ void role_proj(char* smem, const float* __restrict__ x,
                                          const float* __restrict__ W,
                                          const float* __restrict__ b,
                                          __half* __restrict__ hH, int bid) {
    float* A  = (float*)smem;                   // 64*129 floats = 33024 B
    float* Wl = (float*)(smem + 64 * S_X * 4);  // 64*64 floats = 16384 B
    const int t = threadIdx.x;
    const int nb = bid * 64;
    for (int i = t; i < 64 * HID; i += 256) Wl[i] = W[i];   // k = 0..63
    for (int i = t; i < 64 * (IN_DIM / 4); i += 256) {
        const int n = i >> 5;
        const int k4 = (i & 31) * 4;
        float4 val = make_float4(0.f, 0.f, 0.f, 0.f);
        if (nb + n < N_NODES)
            val = *(const float4*)(x + (size_t)(nb + n) * IN_DIM + k4);
        float* dst = &A[n * S_X + k4];
        dst[0] = val.x; dst[1] = val.y; dst[2] = val.z; dst[3] = val.w;
    }
    __syncthreads();

    const int ln = t & 31;
    const int c0 = (t >> 5) * 8;
    float acc[2][8];
#pragma unroll
    for (int j = 0; j < 2; ++j)
#pragma unroll
        for (int c = 0; c < 8; ++c) acc[j][c] = b[c0 + c];
    for (int k = 0; k < 64; ++k) {
        const float a0 = A[ln * S_X + k];
        const float a1 = A[(ln + 32) * S_X + k];
        const float4 wA = *(const float4*)&Wl[k * HID + c0];
        const float4 wB = *(const float4*)&Wl[k * HID + c0 + 4];
        const float w[8] = {wA.x, wA.y, wA.z, wA.w, wB.x, wB.y, wB.z, wB.w};
#pragma unroll
        for (int c = 0; c < 8; ++c) {
            acc[0][c] = fmaf(a0, w[c], acc[0][c]);
            acc[1][c] = fmaf(a1, w[c], acc[1][c]);
        }
    }
    __syncthreads();                                        // Wl half-1 reads done
    for (int i = t; i < 64 * HID; i += 256) Wl[i] = W[64 * HID + i];  // k = 64..127
    __syncthreads();
    for (int k = 64; k < 128; ++k) {
        const float a0 = A[ln * S_X + k];
        const float a1 = A[(ln + 32) * S_X + k];
        const float4 wA = *(const float4*)&Wl[(k - 64) * HID + c0];
        const float4 wB = *(const float4*)&Wl[(k - 64) * HID + c0 + 4];
        const float w[8] = {wA.x, wA.y, wA.z, wA.w, wB.x, wB.y, wB.z, wB.w};
#pragma unroll
        for (int c = 0; c < 8; ++c) {
            acc[0][c] = fmaf(a0, w[c], acc[0][c]);
            acc[1][c] = fmaf(a1, w[c], acc[1][c]);
        }
    }
#pragma unroll
    for (int j = 0; j < 2; ++j) {
        const int n = nb + ln + 32 * j;
        if (n < N_NODES) {
            H8 o;
#pragma unroll
            for (int c = 0; c < 4; ++c)
                o.h[c] = __floats2half2_rn(acc[j][2 * c], acc[j][2 * c + 1]);
            *(float4*)(hH + (size_t)n * HID + c0) = o.f4;
        }
    }
}

__global__ __launch_bounds__(256) void k_front(
        const int* __restrict__ ei, const int* __restrict__ batch,
        const float* __restrict__ x, const float* __restrict__ W,
        const float* __restrict__ b,
        int* __restrict__ gcur, unsigned int* __restrict__ epairs,
        int* __restrict__ gstart, __half* __restrict__ hH) {
    __shared__ __attribute__((aligned(16))) char smem[FRONT_SMEM_BYTES];
    const int bid = blockIdx.x;
    if (bid < BBLK) {
        role_bucket(smem, ei, gcur, epairs, bid);
    } else if (bid < BBLK + NBKT) {
        role_gbound(batch, gstart, bid - BBLK);
    } else {
        role_proj(smem, x, W, b, hH, bid - BBLK - NBKT);
    }
}

// ---------------------------------------------------------------- pass B: per-bucket CSR in LDS
__global__ __launch_bounds__(256) void k_csr(const int* __restrict__ gcur,
                                             const unsigned int* __restrict__ epairs,
                                             int* __restrict__ rowptr,
                                             unsigned short* __restrict__ srclist) {
    __shared__ int lhist[256];
    __shared__ int lcur[256];
    __shared__ int lsrc[BSTRIDE];     // 20.5 KB
    __shared__ int pws[4], wtot[4];
    const int b = blockIdx.x;
    const int t = threadIdx.x;
    const int lane = t & 63, wv = t >> 6;

    int po = 0;
    for (int j = t; j < b; j += 256) po += gcur[j];
#pragma unroll
    for (int m = 32; m; m >>= 1) po += __shfl_xor(po, m, 64);
    if (lane == 0) pws[wv] = po;
    lhist[t] = 0;
    __syncthreads();
    const int base = pws[0] + pws[1] + pws[2] + pws[3];
    const int cnt = gcur[b];

    for (int i = t; i < cnt; i += 256)
        atomicAdd(&lhist[(epairs[b * BSTRIDE + i] >> 16) & 255], 1);
    __syncthreads();

    const int d = lhist[t];
    int incl = d;
#pragma unroll
    for (int off = 1; off < 64; off <<= 1) {
        const int u = __shfl_up(incl, off, 64);
        if (lane >= off) incl += u;
    }
    if (lane == 63) wtot[wv] = incl;
    __syncthreads();
    int woff = 0;
#pragma unroll
    for (int i = 0; i < 4; ++i) woff += (i < wv) ? wtot[i] : 0;
    const int excl = woff + incl - d;
    lcur[t] = excl;
    const int node = b * 256 + t;
    if (node < N_NODES) rowptr[node] = base + excl;
    if (b == NBKT - 1 && t == 0) rowptr[N_NODES] = base + cnt;  // == N_EDGES
    __syncthreads();

    for (int i = t; i < cnt; i += 256) {
        const unsigned int u = epairs[b * BSTRIDE + i];
        const int pos = atomicAdd(&lcur[(u >> 16) & 255], 1);
        lsrc[pos] = (int)(u & 0xFFFFu);
    }
    __syncthreads();
    for (int i = t; i < cnt; i += 256)
        srclist[base + i] = (unsigned short)lsrc[i];
}

// ---------------------------------------------------------------- fused conv: gather + 2-layer MLP
// 64-node tile -> 782 blocks; LDS 32.6 KB -> 4 blocks/CU ceiling.
#define S_A 65
__global__ __launch_bounds__(256, 4) void k_conv(
        const __half* __restrict__ hin,
        const int* __restrict__ rowptr, const unsigned short* __restrict__ srclist,
        const float* __restrict__ W1, const float* __restrict__ b1,
        const float* __restrict__ W2, const float* __restrict__ b2,
        __half* __restrict__ hout) {
    __shared__ float A[64 * S_A];      // 16.6 KB (v, then u)
    __shared__ float Wl[HID * HID];    // 16 KB (W1, then W2)
    const int t = threadIdx.x;
    for (int i = t; i < HID * HID; i += 256) Wl[i] = W1[i];

    const int nb = blockIdx.x * 64;
    const int grp = t >> 3;            // 0..31: node within pass
    const int q = t & 7;               // 8-half chunk of the row
#pragma unroll
    for (int pass = 0; pass < 2; ++pass) {
        const int nloc = pass * 32 + grp;
        const int node = nb + nloc;
        float acc[8] = {0.f, 0.f, 0.f, 0.f, 0.f, 0.f, 0.f, 0.f};
        if (node < N_NODES) {
            acc_h8(acc, *(const float4*)(hin + (size_t)node * HID + q * 8));  // self
            const int beg = rowptr[node];
            const int end = rowptr[node + 1];
            int e = beg;
            for (; e + 8 <= end; e += 8) {
                int s[8];
#pragma unroll
                for (int i = 0; i < 8; ++i) s[i] = srclist[e + i];
                float4 r[8];
#pragma unroll
                for (int i = 0; i < 8; ++i)
                    r[i] = *(const float4*)(hin + (size_t)s[i] * HID + q * 8);
#pragma unroll
                for (int i = 0; i < 8; ++i) acc_h8(acc, r[i]);
            }
            for (; e < end; ++e)
                acc_h8(acc, *(const float4*)(hin + (size_t)srclist[e] * HID + q * 8));
        }
        float* dst = &A[nloc * S_A + q * 8];
#pragma unroll
        for (int i = 0; i < 8; ++i) dst[i] = acc[i];
    }
    __syncthreads();

    const int ln = t & 31;
    const int c0 = (t >> 5) * 8;
    float bb[8];
#pragma unroll
    for (int c = 0; c < 8; ++c) bb[c] = b1[c0 + c];

    float acc2[2][8];
    // ---- layer 1
#pragma unroll
    for (int j = 0; j < 2; ++j)
#pragma unroll
        for (int c = 0; c < 8; ++c) acc2[j][c] = bb[c];
    for (int k = 0; k < HID; ++k) {
        const float a0 = A[ln * S_A + k];
        const float a1 = A[(ln + 32) * S_A + k];
        const float4 wA = *(const float4*)&Wl[k * HID + c0];
        const float4 wB = *(const float4*)&Wl[k * HID + c0 + 4];
        const float w[8] = {wA.x, wA.y, wA.z, wA.w, wB.x, wB.y, wB.z, wB.w};
#pragma unroll
        for (int c = 0; c < 8; ++c) {
            acc2[0][c] = fmaf(a0, w[c], acc2[0][c]);
            acc2[1][c] = fmaf(a1, w[c], acc2[1][c]);
        }
    }
    __syncthreads();   // all layer-1 A and Wl reads complete
    // write u = relu(acc2) into A; stage W2 into Wl
#pragma unroll
    for (int j = 0; j < 2; ++j) {
        float* dst = &A[(ln + 32 * j) * S_A + c0];
#pragma unroll
        for (int c = 0; c < 8; ++c) dst[c] = fmaxf(acc2[j][c], 0.0f);
    }
    for (int i = t; i < HID * HID; i += 256) Wl[i] = W2[i];
#pragma unroll
    for (int c = 0; c < 8; ++c) bb[c] = b2[c0 + c];
    __syncthreads();

    // ---- layer 2
#pragma unroll
    for (int j = 0; j < 2; ++j)
#pragma unroll
        for (int c = 0; c < 8; ++c) acc2[j][c] = bb[c];
    for (int k = 0; k < HID; ++k) {
        const float a0 = A[ln * S_A + k];
        const float a1 = A[(ln + 32) * S_A + k];
        const float4 wA = *(const float4*)&Wl[k * HID + c0];
        const float4 wB = *(const float4*)&Wl[k * HID + c0 + 4];
        const float w[8] = {wA.x, wA.y, wA.z, wA.w, wB.x, wB.y, wB.z, wB.w};
#pragma unroll
        for (int c = 0; c < 8; ++c) {
            acc2[0][c] = fmaf(a0, w[c], acc2[0][c]);
            acc2[1][c] = fmaf(a1, w[c], acc2[1][c]);
        }
    }
#pragma unroll
    for (int j = 0; j < 2; ++j) {
        const int n = nb + ln + 32 * j;
        if (n < N_NODES) {
            H8 o;
#pragma unroll
            for (int c = 0; c < 4; ++c)
                o.h[c] = __floats2half2_rn(fmaxf(acc2[j][2 * c], 0.f),
                                           fmaxf(acc2[j][2 * c + 1], 0.f));
            *(float4*)(hout + (size_t)n * HID + c0) = o.f4;
        }
    }
}

// ---------------------------------------------------------------- fused mean-pool + proj_out
__global__ __launch_bounds__(256) void k_poolout(
        const __half* __restrict__ hin, const int* __restrict__ gstart,
        const float* __restrict__ Wo, const float* __restrict__ bo,
        float* __restrict__ out) {
    __shared__ float Wl[HID * OUT_DIM];   // 32 KB
    __shared__ float red[4][HID];
    __shared__ float mean[HID];
    const int g = blockIdx.x;
    const int t = threadIdx.x;
    for (int i = t; i < HID * OUT_DIM; i += 256) Wl[i] = Wo[i];
    const int c = t & 63;
    const int wv = t >> 6;
    const int beg = gstart[g], end = gstart[g + 1];
    float acc = 0.0f;
    for (int n = beg + wv; n < end; n += 4)
        acc += __half2float(hin[(size_t)n * HID + c]);
    red[wv][c] = acc;
    __syncthreads();
    if (t < HID) {
        const float cnt = (float)(end - beg);
        mean[t] = cnt > 0.0f ? (red[0][t] + red[1][t] + red[2][t] + red[3][t]) / cnt
                             : 0.0f;
    }
    __syncthreads();
    if (t < OUT_DIM) {
        float o = 0.0f;
        for (int k = 0; k < HID; ++k)
            o = fmaf(mean[k], Wl[k * OUT_DIM + t], o);
        out[g * OUT_DIM + t] = (end > beg) ? o + bo[t] : 0.0f;
    }
}

// ---------------------------------------------------------------- launch
extern "C" void kernel_launch(void* const* d_in, const int* in_sizes, int n_in,
                              void* d_out, int out_size, void* d_ws, size_t ws_size,
                              hipStream_t stream) {
    const float* x     = (const float*)d_in[0];
    const int*   ei    = (const int*)d_in[1];
    const int*   batch = (const int*)d_in[2];
    const float* W_in  = (const float*)d_in[3];
    const float* b_in  = (const float*)d_in[4];
    const float* W1_0  = (const float*)d_in[5];
    const float* b1_0  = (const float*)d_in[6];
    const float* W2_0  = (const float*)d_in[7];
    const float* b2_0  = (const float*)d_in[8];
    const float* W1_1  = (const float*)d_in[9];
    const float* b1_1  = (const float*)d_in[10];
    const float* W2_1  = (const float*)d_in[11];
    const float* b2_1  = (const float*)d_in[12];
    const float* W_out = (const float*)d_in[13];
    const float* b_out = (const float*)d_in[14];
    float* out = (float*)d_out;

    unsigned int*   wsw    = (unsigned int*)d_ws;
    int*            gcur   = (int*)(wsw + OFF_GCUR);
    int*            gstart = (int*)(wsw + OFF_GSTART);
    int*            rowptr = (int*)(wsw + OFF_ROWPTR);
    unsigned short* srcl   = (unsigned short*)(wsw + OFF_SRCL);
    unsigned int*   epairs = (unsigned int*)(wsw + OFF_EPAIRS);
    __half*         hA     = (__half*)(wsw + OFF_HA);
    __half*         hB     = (__half*)(wsw + OFF_HB);

    const int pi_blocks = (N_NODES + 63) / 64;            // 782
    const int cv_blocks = (N_NODES + 63) / 64;            // 782
    const int front_blocks = BBLK + NBKT + pi_blocks;     // 1370

    k_zero<<<1, 256, 0, stream>>>(gcur, NBKT);
    k_front<<<front_blocks, 256, 0, stream>>>(ei, batch, x, W_in, b_in,
                                              gcur, epairs, gstart, hA);
    k_csr<<<NBKT, 256, 0, stream>>>(gcur, epairs, rowptr, srcl);
    k_conv<<<cv_blocks, 256, 0, stream>>>(hA, rowptr, srcl, W1_0, b1_0, W2_0, b2_0, hB);
    k_conv<<<cv_blocks, 256, 0, stream>>>(hB, rowptr, srcl, W1_1, b1_1, W2_1, b2_1, hA);
    k_poolout<<<N_GRAPHS, 256, 0, stream>>>(hA, gstart, W_out, b_out, out);
}